// Round 4
// baseline (1494.176 us; speedup 1.0000x reference)
//
#include <hip/hip_runtime.h>
#include <stdint.h>

#define NN 50000
#define H 150
#define NE 400000
#define NG 64
#define NPASS 5
#define KB 480          // GRU GEMM K: [S0(160) | S1(160) | nodes(160)]
#define VC 640          // 40 col-tiles: v = cc*64 + g*16 + cl, c = cc*16+cl
#define NRB 391         // row blocks of 128

typedef unsigned short u16;
typedef unsigned int u32;
typedef __attribute__((ext_vector_type(8))) short short8;
typedef __attribute__((ext_vector_type(4))) float float4v;
typedef __attribute__((ext_vector_type(4))) u32 uint4v;
typedef __attribute__((ext_vector_type(2))) u32 uint2v;

// ---------------- helpers ----------------
__device__ __forceinline__ u16 f2bf_rn(float x) {
  union { float f; u32 u; } v; v.f = x;
  u32 r = v.u + 0x7fffu + ((v.u >> 16) & 1u);
  return (u16)(r >> 16);
}
__device__ __forceinline__ float bf2f(u16 h) {
  union { u32 u; float f; } v; v.u = ((u32)h) << 16;
  return v.f;
}
// packed word: low16 = hi bf16, high16 = lo bf16; value = hi + lo
__device__ __forceinline__ u32 packf(float v) {
  u16 hi = f2bf_rn(v);
  u16 lo = f2bf_rn(v - bf2f(hi));
  return (u32)hi | ((u32)lo << 16);
}
__device__ __forceinline__ float upk(u32 u) {
  union { u32 u; float f; } a, b;
  a.u = u << 16; b.u = u & 0xffff0000u;
  return a.f + b.f;
}

// ---------------- CSR build (key = node*2 + set) ----------------
__global__ void hist_kernel(const int* __restrict__ edges, int* __restrict__ cnt) {
  int id = blockIdx.x * 256 + threadIdx.x;
  if (id >= 2 * NE) return;
  int dst = edges[id * 2];
  int set = id / NE;
  atomicAdd(&cnt[dst * 2 + set], 1);
}

__global__ __launch_bounds__(1024) void scan1_kernel(const int* __restrict__ cnt,
                                                     int* __restrict__ rowptr,
                                                     int* __restrict__ bsum, int n) {
  __shared__ int sd[1024];
  int t = threadIdx.x;
  int idx = blockIdx.x * 1024 + t;
  int v = (idx < n) ? cnt[idx] : 0;
  sd[t] = v;
  __syncthreads();
  for (int off = 1; off < 1024; off <<= 1) {
    int add = (t >= off) ? sd[t - off] : 0;
    __syncthreads();
    sd[t] += add;
    __syncthreads();
  }
  if (idx < n) rowptr[idx] = sd[t] - v;     // block-local exclusive
  if (t == 1023) bsum[blockIdx.x] = sd[1023];
}

__global__ __launch_bounds__(128) void scan2_kernel(const int* __restrict__ bsum,
                                                    int* __restrict__ boff, int nb) {
  __shared__ int sd[128];
  int t = threadIdx.x;
  int v = (t < nb) ? bsum[t] : 0;
  sd[t] = v;
  __syncthreads();
  for (int off = 1; off < 128; off <<= 1) {
    int add = (t >= off) ? sd[t - off] : 0;
    __syncthreads();
    sd[t] += add;
    __syncthreads();
  }
  boff[t] = sd[t] - v;                       // exclusive; boff[nb] = total
}

__global__ void scan3_kernel(int* __restrict__ rowptr, const int* __restrict__ boff, int n) {
  int idx = blockIdx.x * 256 + threadIdx.x;
  if (idx < n) rowptr[idx] += boff[idx >> 10];
}

__global__ void total_kernel(int* __restrict__ rowptr, const int* __restrict__ boff, int n, int nb) {
  if (threadIdx.x == 0 && blockIdx.x == 0) rowptr[n] = boff[nb];
}

__global__ void copy_int_kernel(const int* __restrict__ a, int* __restrict__ b, int n) {
  int id = blockIdx.x * 256 + threadIdx.x;
  if (id < n) b[id] = a[id];
}

__global__ void fill_kernel(const int* __restrict__ edges, int* __restrict__ cursor,
                            u16* __restrict__ colbuf) {
  int id = blockIdx.x * 256 + threadIdx.x;
  if (id >= 2 * NE) return;
  int dst = edges[id * 2];
  int src = edges[id * 2 + 1];
  int set = id / NE;
  int pos = atomicAdd(&cursor[dst * 2 + set], 1);
  colbuf[pos] = (u16)src;
}

__global__ void bounds_kernel(const int* __restrict__ gids, int* __restrict__ gstart) {
  int g = threadIdx.x;
  if (g > NG) return;
  int lo = 0, hi = NN;
  while (lo < hi) { int m = (lo + hi) >> 1; if (gids[m] < g) lo = m + 1; else hi = m; }
  gstart[g] = lo;
}

// ---------------- one-time weight prep ----------------
// B'[v][k], v in [0,640): g=(v>>4)&3, c=(v>>6)*16+(v&15)
// k<160: (W_ihg @ W0)[c][k]      (g<3; g3=0)
// 160<=k<320: (W_ihg @ W1)[c][k-160]
// 320<=k<480: g0: w_hh[c][kk], g1: w_hh[150+c][kk], g3: w_hh[300+c][kk], g2: 0
__global__ void build_B_kernel(const float* __restrict__ wih, const float* __restrict__ whh,
                               const float* __restrict__ eW,
                               u16* __restrict__ Bh, u16* __restrict__ Bl) {
  int id = blockIdx.x * 256 + threadIdx.x;
  if (id >= VC * KB) return;
  int v = id / KB, k = id % KB;
  int g = (v >> 4) & 3, c = (v >> 6) * 16 + (v & 15);
  int seg = k / 160, kk = k % 160;
  float val = 0.f;
  if (c < H && kk < H) {
    if (seg < 2) {
      if (g < 3) {
        const float* wr = wih + (size_t)(g * H + c) * H;
        const float* wc = eW + (size_t)seg * H * H + kk;
        float acc = 0.f;
        for (int t = 0; t < H; t++) acc += wr[t] * wc[(size_t)t * H];
        val = acc;
      }
    } else {
      if (g == 0) val = whh[(size_t)c * H + kk];
      else if (g == 1) val = whh[(size_t)(H + c) * H + kk];
      else if (g == 3) val = whh[(size_t)(2 * H + c) * H + kk];
    }
  }
  u16 h = f2bf_rn(val);
  Bh[id] = h;
  Bl[id] = f2bf_rn(val - bf2f(h));
}

// coefs[0][g*160+c] = W_ihg @ b0 (deg0 coef), coefs[1] = W_ihg @ b1, coefs[2] = gate bias
__global__ void build_coef_kernel(const float* __restrict__ wih,
                                  const float* __restrict__ eb,
                                  const float* __restrict__ bih, const float* __restrict__ bhh,
                                  float* __restrict__ coefs) {
  int id = threadIdx.x + blockIdx.x * 256;
  if (id >= VC) return;
  int g = id / 160, c = id % 160;
  float u0 = 0.f, u1 = 0.f, bs = 0.f;
  if (c < H) {
    if (g < 3) {
      const float* wr = wih + (size_t)(g * H + c) * H;
      for (int t = 0; t < H; t++) { u0 += wr[t] * eb[t]; u1 += wr[t] * eb[H + t]; }
    }
    if (g == 0) bs = bih[c] + bhh[c];
    else if (g == 1) bs = bih[H + c] + bhh[H + c];
    else if (g == 2) bs = bih[2 * H + c];
    else bs = bhh[2 * H + c];
  }
  coefs[id] = u0;
  coefs[VC + id] = u1;
  coefs[2 * VC + id] = bs;
}

// pack input nodes into npkA; zero pad cols of both buffers
__global__ void init_nodes_kernel(const float* __restrict__ nin,
                                  u32* __restrict__ npkA, u32* __restrict__ npkB) {
  int id = blockIdx.x * 256 + threadIdx.x;
  if (id >= NN * 160) return;
  int r = id / 160, c = id % 160;
  if (c < H) {
    npkA[id] = packf(nin[(size_t)r * H + c]);
  } else {
    npkA[id] = 0;
    npkB[id] = 0;
  }
}

// zero the pad columns of packed S (cols 150..159 per set) — gather never writes them
__global__ void pad_S_kernel(u32* __restrict__ Snp) {
  int id = blockIdx.x * 256 + threadIdx.x;
  if (id >= NN * 20) return;
  int r = id / 20, rem = id % 20;
  int set = rem / 10, t = rem % 10;
  Snp[(size_t)r * 320 + set * 160 + H + t] = 0;
}

// ---------------- gather: Snp[n][set*160+c] = packed sum of raw node rows ------
// R14 structure kept: adjacency list loaded coalesced once, src broadcast via
// readlane, 4-edge unroll. Bit-identical accumulation order.
__global__ __launch_bounds__(256) void gather_kernel(
    const u32* __restrict__ npk, const int* __restrict__ rowptr,
    const u16* __restrict__ colbuf, u32* __restrict__ Snp) {
  int gtid = blockIdx.x * 256 + threadIdx.x;
  int wid = gtid >> 6;
  if (wid >= 2 * NN) return;
  int node = wid >> 1, set = wid & 1;
  int lane = gtid & 63;
  int s = rowptr[2 * node + set], e = rowptr[2 * node + set + 1];
  int deg = e - s;
  int cA = 2 * lane, cC = 128 + lane;
  bool okC = (cC < H);                 // lanes 0..21
  float aA = 0.f, aB = 0.f, aC = 0.f;
  for (int base = 0; base < deg; base += 64) {
    int rem = min(64, deg - base);
    u32 srcv = 0;
    if (lane < rem) srcv = (u32)colbuf[s + base + lane];
    int i = 0;
    for (; i + 3 < rem; i += 4) {
      u32 r0 = (u32)__builtin_amdgcn_readlane((int)srcv, i);
      u32 r1 = (u32)__builtin_amdgcn_readlane((int)srcv, i + 1);
      u32 r2 = (u32)__builtin_amdgcn_readlane((int)srcv, i + 2);
      u32 r3 = (u32)__builtin_amdgcn_readlane((int)srcv, i + 3);
      const u32* p0 = npk + (size_t)r0 * 160;
      const u32* p1 = npk + (size_t)r1 * 160;
      const u32* p2 = npk + (size_t)r2 * 160;
      const u32* p3 = npk + (size_t)r3 * 160;
      uint2v v0 = *(const uint2v*)(p0 + cA);
      uint2v v1 = *(const uint2v*)(p1 + cA);
      uint2v v2 = *(const uint2v*)(p2 + cA);
      uint2v v3 = *(const uint2v*)(p3 + cA);
      u32 w0 = 0, w1 = 0, w2 = 0, w3 = 0;
      if (okC) { w0 = p0[cC]; w1 = p1[cC]; w2 = p2[cC]; w3 = p3[cC]; }
      aA += upk(v0.x) + upk(v1.x);
      aB += upk(v0.y) + upk(v1.y);
      if (okC) aC += upk(w0) + upk(w1);
      aA += upk(v2.x) + upk(v3.x);
      aB += upk(v2.y) + upk(v3.y);
      if (okC) aC += upk(w2) + upk(w3);
    }
    for (; i + 1 < rem; i += 2) {
      u32 r0 = (u32)__builtin_amdgcn_readlane((int)srcv, i);
      u32 r1 = (u32)__builtin_amdgcn_readlane((int)srcv, i + 1);
      const u32* p0 = npk + (size_t)r0 * 160;
      const u32* p1 = npk + (size_t)r1 * 160;
      uint2v v0 = *(const uint2v*)(p0 + cA);
      uint2v v1 = *(const uint2v*)(p1 + cA);
      aA += upk(v0.x) + upk(v1.x);
      aB += upk(v0.y) + upk(v1.y);
      if (okC) aC += upk(p0[cC]) + upk(p1[cC]);
    }
    if (i < rem) {
      u32 r0 = (u32)__builtin_amdgcn_readlane((int)srcv, i);
      const u32* p0 = npk + (size_t)r0 * 160;
      uint2v v0 = *(const uint2v*)(p0 + cA);
      aA += upk(v0.x);
      aB += upk(v0.y);
      if (okC) aC += upk(p0[cC]);
    }
  }
  u32* o = Snp + (size_t)node * 320 + set * 160;
  o[cA] = packf(aA);
  o[cA + 1] = packf(aB);
  if (okC) o[cC] = packf(aC);
}

// ---------------- fused GRU GEMM — R15: NO LDS, NO BARRIERS ----------------
// Both operands stream global -> VGPR directly:
//   A frag: lane (m,quad) loads 2x uint4 (32B contiguous) from its OWN row
//           (Snp for kt<10, npkc for kt>=10) — same values the LDS path staged.
//   B frag: lane loads 2x short8 (16B) from Bh/Bl — B is 1.2MB, L2/LLC-resident
//           with 391x reuse across row-blocks.
// Depth-2 register pipeline, 14 loads/step/wave (8 A + 6 B), uniform across
// waves: step kt = { s_waitcnt vmcnt(14); MFMA(kt); issue loads(kt+2) }.
// vmcnt(14) leaves loads(kt+1) in flight, drains loads(kt). No __syncthreads
// anywhere: waves fully independent. sched_barrier(0) after waitcnt pins MFMA
// (rule: compiler hoists reg-only MFMA past inline-asm waitcnt). Buffers are
// constexpr-indexed (no scratch). MFMA order identical -> bit-identical output.

template<int KT>
__device__ __forceinline__ void mfma_fn(
    const uint4v (&A0)[4], const uint4v (&A1)[4],
    const short8 (&MBh)[3], const short8 (&MBl)[3], float4v (&acc)[4][4]) {
  #pragma unroll
  for (int mt = 0; mt < 4; mt++) {
    u32 uu[8] = {A0[mt].x, A0[mt].y, A0[mt].z, A0[mt].w,
                 A1[mt].x, A1[mt].y, A1[mt].z, A1[mt].w};
    short8 ah, al;
    #pragma unroll
    for (int e2 = 0; e2 < 8; e2++) {
      ah[e2] = (short)(uu[e2] & 0xffffu);
      al[e2] = (short)(uu[e2] >> 16);
    }
    #pragma unroll
    for (int jj = 0; jj < 3; jj++) {
      const int J = (KT < 10) ? jj : ((jj == 2) ? 3 : jj);
      acc[mt][J] = __builtin_amdgcn_mfma_f32_16x16x32_bf16(ah, MBh[jj], acc[mt][J], 0, 0, 0);
      acc[mt][J] = __builtin_amdgcn_mfma_f32_16x16x32_bf16(ah, MBl[jj], acc[mt][J], 0, 0, 0);
      acc[mt][J] = __builtin_amdgcn_mfma_f32_16x16x32_bf16(al, MBh[jj], acc[mt][J], 0, 0, 0);
    }
  }
}

// issue the 14 frag loads for step KT into buffer BUF (no-op past the end)
template<int KT, int BUF>
__device__ __forceinline__ void load_frags(
    const u32* const (&aS)[4], const u32* const (&aN)[4],
    const u16* __restrict__ Bhp, const u16* __restrict__ Blp,
    const u32 (&bo1)[3], const u32 (&bo2)[3],
    uint4v (&A0)[2][4], uint4v (&A1)[2][4],
    short8 (&FBh)[2][3], short8 (&FBl)[2][3]) {
  if constexpr (KT <= 14) {
    #pragma unroll
    for (int mt = 0; mt < 4; mt++) {
      const u32* p = (KT < 10) ? (aS[mt] + KT * 32) : (aN[mt] + (KT - 10) * 32);
      A0[BUF][mt] = *(const uint4v*)p;
      A1[BUF][mt] = *(const uint4v*)(p + 4);
    }
    constexpr int koffB = (KT < 10) ? KT * 32 : 320 + (KT - 10) * 32;
    #pragma unroll
    for (int jj = 0; jj < 3; jj++) {
      u32 off = ((KT < 10) ? bo1[jj] : bo2[jj]) + koffB;
      FBh[BUF][jj] = *(const short8*)(Bhp + off);
      FBl[BUF][jj] = *(const short8*)(Blp + off);
    }
  }
}

template<int KT>
__device__ __forceinline__ void gemm_step(
    const u32* const (&aS)[4], const u32* const (&aN)[4],
    const u16* __restrict__ Bhp, const u16* __restrict__ Blp,
    const u32 (&bo1)[3], const u32 (&bo2)[3],
    uint4v (&A0)[2][4], uint4v (&A1)[2][4],
    short8 (&FBh)[2][3], short8 (&FBl)[2][3], float4v (&acc)[4][4]) {
  constexpr int cur = KT & 1;
  // drain loads(KT); leave loads(KT+1) (14) in flight
  if constexpr (KT + 1 <= 14) {
    asm volatile("s_waitcnt vmcnt(14)" ::: "memory");
  } else {
    asm volatile("s_waitcnt vmcnt(0)" ::: "memory");
  }
  __builtin_amdgcn_sched_barrier(0);
  __builtin_amdgcn_s_setprio(1);
  mfma_fn<KT>(A0[cur], A1[cur], FBh[cur], FBl[cur], acc);
  __builtin_amdgcn_s_setprio(0);
  __builtin_amdgcn_sched_barrier(0);
  // buf[cur] now consumed — refill with loads(KT+2)
  load_frags<KT + 2, cur>(aS, aN, Bhp, Blp, bo1, bo2, A0, A1, FBh, FBl);
  __builtin_amdgcn_sched_barrier(0);
}

__global__ __launch_bounds__(256, 2) void gru_gemm_kernel(
    const u32* __restrict__ Snp, const u32* __restrict__ npkc,
    const u16* __restrict__ Bhp, const u16* __restrict__ Blp,
    const float* __restrict__ coefs, const int* __restrict__ rowptr,
    u32* __restrict__ npkn) {
  const int bid = blockIdx.x;
  const int xcd = bid & 7;
  const int rest = bid >> 3;
  const int ccb = rest % 5;
  const int r0b = (rest / 5) * 8 + xcd;
  if (r0b >= NRB) return;
  const int r0 = r0b * 128;
  const int tid = threadIdx.x;
  const int w = tid >> 6, l = tid & 63;
  const int m = l & 15, quad = l >> 4;
  const int mrow0 = (w & 1) * 64;
  const int nco0 = (w >> 1) * 64;

  // per-lane A row base pointers (include the quad's 8-u32 K-chunk offset)
  const u32* aS[4];
  const u32* aN[4];
  #pragma unroll
  for (int mt = 0; mt < 4; mt++) {
    int rg = min(r0 + mrow0 + mt * 16 + m, NN - 1);
    aS[mt] = Snp + (size_t)rg * 320 + quad * 8;
    aN[mt] = npkc + (size_t)rg * 160 + quad * 8;
  }
  // per-lane B element offsets (u16 units): row (ccb*128 + nco0 + jsel*16 + m)
  u32 bo1[3], bo2[3];
  {
    const int bc = ccb * 128 + nco0;
    #pragma unroll
    for (int jj = 0; jj < 3; jj++) {
      const int js1 = jj;                        // gates r,z,n  (kt<10)
      const int js2 = (jj == 2) ? 3 : jj;        // gates r,z,h  (kt>=10)
      bo1[jj] = (u32)(bc + js1 * 16 + m) * KB + quad * 8;
      bo2[jj] = (u32)(bc + js2 * 16 + m) * KB + quad * 8;
    }
  }

  float4v acc[4][4];
  #pragma unroll
  for (int mt = 0; mt < 4; mt++)
    #pragma unroll
    for (int j = 0; j < 4; j++) acc[mt][j] = (float4v){0.f, 0.f, 0.f, 0.f};

  uint4v A0[2][4], A1[2][4];
  short8 FBh[2][3], FBl[2][3];

  // ---- prologue: fill both register buffers ----
  load_frags<0, 0>(aS, aN, Bhp, Blp, bo1, bo2, A0, A1, FBh, FBl);
  __builtin_amdgcn_sched_barrier(0);
  load_frags<1, 1>(aS, aN, Bhp, Blp, bo1, bo2, A0, A1, FBh, FBl);
  __builtin_amdgcn_sched_barrier(0);

  // ---- 15 fully-unrolled K-steps, no barriers ----
  #define STEP(K) gemm_step<K>(aS, aN, Bhp, Blp, bo1, bo2, A0, A1, FBh, FBl, acc)
  STEP(0);  STEP(1);  STEP(2);  STEP(3);  STEP(4);
  STEP(5);  STEP(6);  STEP(7);  STEP(8);  STEP(9);
  STEP(10); STEP(11); STEP(12); STEP(13); STEP(14);
  #undef STEP

  // ---- epilogue: wave handles c-chunk cc = ccb*2 + (w>>1); tile j = gate ----
  int c = (ccb * 2 + (w >> 1)) * 16 + m;
  if (c >= H) return;
  float u0r = coefs[c],            u0z = coefs[160 + c],
        u0n = coefs[320 + c];
  float u1r = coefs[VC + c],       u1z = coefs[VC + 160 + c],
        u1n = coefs[VC + 320 + c];
  float bsr = coefs[2 * VC + c],   bsz = coefs[2 * VC + 160 + c],
        bsn = coefs[2 * VC + 320 + c], bsh = coefs[2 * VC + 480 + c];
  #pragma unroll
  for (int mt = 0; mt < 4; mt++) {
    #pragma unroll
    for (int i = 0; i < 4; i++) {
      int row = r0 + mrow0 + mt * 16 + quad * 4 + i;
      if (row >= NN) continue;
      float d0 = (float)(rowptr[2 * row + 1] - rowptr[2 * row]);
      float d1 = (float)(rowptr[2 * row + 2] - rowptr[2 * row + 1]);
      float pr = acc[mt][0][i] + d0 * u0r + d1 * u1r + bsr;
      float pz = acc[mt][1][i] + d0 * u0z + d1 * u1z + bsz;
      float pn = acc[mt][2][i] + d0 * u0n + d1 * u1n + bsn;
      float ph = acc[mt][3][i] + bsh;
      float r_g = 1.f / (1.f + __expf(-pr));
      float z_g = 1.f / (1.f + __expf(-pz));
      float narg = pn + r_g * ph;
      float e2 = __expf(2.f * narg);
      float n_g = 1.f - 2.f / (e2 + 1.f);       // tanh, inf-safe
      float h = upk(npkc[(size_t)row * 160 + c]);
      npkn[(size_t)row * 160 + c] = packf((1.f - z_g) * n_g + z_g * h);
    }
  }
}

// ---------------- readout ----------------
__global__ __launch_bounds__(192) void segsum_kernel(const u32* __restrict__ npk,
                                                     const int* __restrict__ gstart,
                                                     float* __restrict__ gsum) {
  int g = blockIdx.x, chunk = blockIdx.y;
  int c = threadIdx.x;
  if (c >= H) return;
  int s = gstart[g], e = gstart[g + 1];
  int len = e - s;
  if (len <= 0) return;
  int per = (len + 3) / 4;
  int rs = s + chunk * per;
  int re = min(e, rs + per);
  if (rs >= re) return;
  float acc = 0.f;
  for (int r = rs; r < re; r++) acc += upk(npk[(size_t)r * 160 + c]);
  atomicAdd(&gsum[g * H + c], acc);
}

// one block per graph row; 192 thr. LDS: x[151], x1[80], x2[80].
__global__ __launch_bounds__(192) void head_kernel(
    const float* __restrict__ gsum, const float* __restrict__ pt,
    const float* __restrict__ fc1_w, const float* __restrict__ fc1_b,
    const float* __restrict__ fc2_w, const float* __restrict__ fc2_b,
    const float* __restrict__ fcL_w, const float* __restrict__ fcL_b,
    float* __restrict__ out) {
  __shared__ float x[151];
  __shared__ float x1[80];
  __shared__ float x2[80];
  int row = blockIdx.x;
  int t = threadIdx.x;
  if (t < 151) {
    float v;
    if (t < H) { float g = gsum[row * H + t]; v = (g > 1.f) ? logf(g) : 0.f; }
    else v = pt[row];
    x[t] = v;
  }
  __syncthreads();
  if (t < 80) {
    float acc = fc1_b[t];
    const float* wrow = fc1_w + t * 151;
    #pragma unroll 4
    for (int k = 0; k < 151; k++) acc += x[k] * wrow[k];
    x1[t] = (acc > 0.f) ? acc : 0.01f * acc;
  }
  __syncthreads();
  if (t < 80) {
    float acc = fc2_b[t];
    const float* wrow = fc2_w + t * 80;
    #pragma unroll 4
    for (int k = 0; k < 80; k++) acc += x1[k] * wrow[k];
    x2[t] = (acc > 0.f) ? acc : 0.01f * acc;
  }
  __syncthreads();
  if (t < 10) {
    float acc = fcL_b[t];
    const float* wrow = fcL_w + t * 80;
    #pragma unroll 4
    for (int k = 0; k < 80; k++) acc += x2[k] * wrow[k];
    out[row * 10 + t] = acc;
  }
}

extern "C" void kernel_launch(void* const* d_in, const int* in_sizes, int n_in,
                              void* d_out, int out_size, void* d_ws, size_t ws_size,
                              hipStream_t stream) {
  const float* nodes_in = (const float*)d_in[0];
  const float* problem_type = (const float*)d_in[1];
  const float* edge_W = (const float*)d_in[2];
  const float* edge_b = (const float*)d_in[3];
  const float* w_ih = (const float*)d_in[4];
  const float* w_hh = (const float*)d_in[5];
  const float* b_ih = (const float*)d_in[6];
  const float* b_hh = (const float*)d_in[7];
  const float* fc1_w = (const float*)d_in[8];
  const float* fc1_b = (const float*)d_in[9];
  const float* fc2_w = (const float*)d_in[10];
  const float* fc2_b = (const float*)d_in[11];
  const float* fcL_w = (const float*)d_in[12];
  const float* fcL_b = (const float*)d_in[13];
  const int* edges = (const int*)d_in[14];
  const int* graph_ids = (const int*)d_in[15];

  char* ws = (char*)d_ws;
  size_t off = 0;
  auto alloc = [&](size_t bytes) -> void* {
    void* p = ws + off;
    off = (off + bytes + 255) & ~(size_t)255;
    return p;
  };
  u32* npkA     = (u32*)alloc((size_t)NN * 160 * 4);           // 32 MB
  u32* npkB     = (u32*)alloc((size_t)NN * 160 * 4);           // 32 MB
  u32* Snp      = (u32*)alloc((size_t)NN * 320 * 4);           // 64 MB packed S
  u16* Bh       = (u16*)alloc((size_t)VC * KB * 2);            // 0.61 MB
  u16* Bl       = (u16*)alloc((size_t)VC * KB * 2);            // 0.61 MB
  float* coefs  = (float*)alloc(3 * VC * 4);
  int* rowptr   = (int*)alloc((2 * NN + 1) * 4);
  int* cursor   = (int*)alloc(2 * NN * 4);
  u16* colbuf   = (u16*)alloc(2ull * NE * 2);                  // 1.6 MB
  int* bsum     = (int*)alloc(128 * 4);
  int* boff     = (int*)alloc(128 * 4);
  int* gstart   = (int*)alloc((NG + 1) * 4);
  float* gsum   = (float*)alloc((size_t)NG * H * 4);

  const int n2 = 2 * NN;                 // 100000 counters
  const int nb = (n2 + 1023) / 1024;     // 98 scan blocks

  // ---- one-time setup ----
  hipMemsetAsync(cursor, 0, n2 * 4, stream);
  hist_kernel<<<(2 * NE + 255) / 256, 256, 0, stream>>>(edges, cursor);
  scan1_kernel<<<nb, 1024, 0, stream>>>(cursor, rowptr, bsum, n2);
  scan2_kernel<<<1, 128, 0, stream>>>(bsum, boff, nb);
  scan3_kernel<<<(n2 + 255) / 256, 256, 0, stream>>>(rowptr, boff, n2);
  total_kernel<<<1, 64, 0, stream>>>(rowptr, boff, n2, nb);
  copy_int_kernel<<<(n2 + 255) / 256, 256, 0, stream>>>(rowptr, cursor, n2);
  fill_kernel<<<(2 * NE + 255) / 256, 256, 0, stream>>>(edges, cursor, colbuf);
  bounds_kernel<<<1, 128, 0, stream>>>(graph_ids, gstart);
  build_B_kernel<<<(VC * KB + 255) / 256, 256, 0, stream>>>(w_ih, w_hh, edge_W, Bh, Bl);
  build_coef_kernel<<<(VC + 255) / 256, 256, 0, stream>>>(w_ih, edge_b, b_ih, b_hh, coefs);
  init_nodes_kernel<<<(NN * 160 + 255) / 256, 256, 0, stream>>>(nodes_in, npkA, npkB);
  pad_S_kernel<<<(NN * 20 + 255) / 256, 256, 0, stream>>>(Snp);

  // ---- 5 message-passing iterations (packed nodes ping-pong) ----
  const int ngrp = (NRB + 7) / 8;        // 49 groups of 8 row-blocks
  u32* nbuf[2] = {npkA, npkB};
  for (int pass = 0; pass < NPASS; pass++) {
    u32* cur = nbuf[pass & 1];
    u32* nxt = nbuf[1 - (pass & 1)];
    gather_kernel<<<(2 * NN * 64 + 255) / 256, 256, 0, stream>>>(cur, rowptr, colbuf, Snp);
    gru_gemm_kernel<<<ngrp * 5 * 8, 256, 0, stream>>>(
        Snp, cur, Bh, Bl, coefs, rowptr, nxt);
  }
  u32* fin = nbuf[NPASS & 1];

  // ---- readout ----
  hipMemsetAsync(gsum, 0, (size_t)NG * H * 4, stream);
  segsum_kernel<<<dim3(NG, 4), 192, 0, stream>>>(fin, gstart, gsum);
  head_kernel<<<NG, 192, 0, stream>>>(gsum, problem_type, fc1_w, fc1_b, fc2_w, fc2_b,
                                      fcL_w, fcL_b, (float*)d_out);
}

// Round 5
// 1128.609 us; speedup vs baseline: 1.3239x; 1.3239x over previous
//
#include <hip/hip_runtime.h>
#include <stdint.h>

#define NN 50000
#define H 150
#define NE 400000
#define NG 64
#define NPASS 5
#define KB 480          // GRU GEMM K: [S0(160) | S1(160) | nodes(160)]
#define VC 640          // 40 col-tiles: v = cc*64 + g*16 + cl, c = cc*16+cl
#define NRB 391         // row blocks of 128

typedef unsigned short u16;
typedef unsigned int u32;
typedef __attribute__((ext_vector_type(8))) short short8;
typedef __attribute__((ext_vector_type(4))) float float4v;
typedef __attribute__((ext_vector_type(4))) u32 uint4v;
typedef __attribute__((ext_vector_type(2))) u32 uint2v;

// ---------------- helpers ----------------
__device__ __forceinline__ u16 f2bf_rn(float x) {
  union { float f; u32 u; } v; v.f = x;
  u32 r = v.u + 0x7fffu + ((v.u >> 16) & 1u);
  return (u16)(r >> 16);
}
__device__ __forceinline__ float bf2f(u16 h) {
  union { u32 u; float f; } v; v.u = ((u32)h) << 16;
  return v.f;
}
// packed word: low16 = hi bf16, high16 = lo bf16; value = hi + lo
__device__ __forceinline__ u32 packf(float v) {
  u16 hi = f2bf_rn(v);
  u16 lo = f2bf_rn(v - bf2f(hi));
  return (u32)hi | ((u32)lo << 16);
}
__device__ __forceinline__ float upk(u32 u) {
  union { u32 u; float f; } a, b;
  a.u = u << 16; b.u = u & 0xffff0000u;
  return a.f + b.f;
}
// async global->LDS, 16B per lane; lds dest must be wave-uniform base
__device__ __forceinline__ void async16(const void* g, void* l) {
  __builtin_amdgcn_global_load_lds(
      (const __attribute__((address_space(1))) unsigned int*)(uintptr_t)g,
      (__attribute__((address_space(3))) unsigned int*)(uint32_t)(uintptr_t)l,
      16, 0, 0);
}

// ---------------- CSR build (key = node*2 + set) ----------------
__global__ void hist_kernel(const int* __restrict__ edges, int* __restrict__ cnt) {
  int id = blockIdx.x * 256 + threadIdx.x;
  if (id >= 2 * NE) return;
  int dst = edges[id * 2];
  int set = id / NE;
  atomicAdd(&cnt[dst * 2 + set], 1);
}

__global__ __launch_bounds__(1024) void scan1_kernel(const int* __restrict__ cnt,
                                                     int* __restrict__ rowptr,
                                                     int* __restrict__ bsum, int n) {
  __shared__ int sd[1024];
  int t = threadIdx.x;
  int idx = blockIdx.x * 1024 + t;
  int v = (idx < n) ? cnt[idx] : 0;
  sd[t] = v;
  __syncthreads();
  for (int off = 1; off < 1024; off <<= 1) {
    int add = (t >= off) ? sd[t - off] : 0;
    __syncthreads();
    sd[t] += add;
    __syncthreads();
  }
  if (idx < n) rowptr[idx] = sd[t] - v;     // block-local exclusive
  if (t == 1023) bsum[blockIdx.x] = sd[1023];
}

__global__ __launch_bounds__(128) void scan2_kernel(const int* __restrict__ bsum,
                                                    int* __restrict__ boff, int nb) {
  __shared__ int sd[128];
  int t = threadIdx.x;
  int v = (t < nb) ? bsum[t] : 0;
  sd[t] = v;
  __syncthreads();
  for (int off = 1; off < 128; off <<= 1) {
    int add = (t >= off) ? sd[t - off] : 0;
    __syncthreads();
    sd[t] += add;
    __syncthreads();
  }
  boff[t] = sd[t] - v;                       // exclusive; boff[nb] = total
}

__global__ void scan3_kernel(int* __restrict__ rowptr, const int* __restrict__ boff, int n) {
  int idx = blockIdx.x * 256 + threadIdx.x;
  if (idx < n) rowptr[idx] += boff[idx >> 10];
}

__global__ void total_kernel(int* __restrict__ rowptr, const int* __restrict__ boff, int n, int nb) {
  if (threadIdx.x == 0 && blockIdx.x == 0) rowptr[n] = boff[nb];
}

__global__ void copy_int_kernel(const int* __restrict__ a, int* __restrict__ b, int n) {
  int id = blockIdx.x * 256 + threadIdx.x;
  if (id < n) b[id] = a[id];
}

__global__ void fill_kernel(const int* __restrict__ edges, int* __restrict__ cursor,
                            u16* __restrict__ colbuf) {
  int id = blockIdx.x * 256 + threadIdx.x;
  if (id >= 2 * NE) return;
  int dst = edges[id * 2];
  int src = edges[id * 2 + 1];
  int set = id / NE;
  int pos = atomicAdd(&cursor[dst * 2 + set], 1);
  colbuf[pos] = (u16)src;
}

__global__ void bounds_kernel(const int* __restrict__ gids, int* __restrict__ gstart) {
  int g = threadIdx.x;
  if (g > NG) return;
  int lo = 0, hi = NN;
  while (lo < hi) { int m = (lo + hi) >> 1; if (gids[m] < g) lo = m + 1; else hi = m; }
  gstart[g] = lo;
}

// ---------------- one-time weight prep ----------------
// B'[v][k], v in [0,640): g=(v>>4)&3, c=(v>>6)*16+(v&15)
// k<160: (W_ihg @ W0)[c][k]      (g<3; g3=0)
// 160<=k<320: (W_ihg @ W1)[c][k-160]
// 320<=k<480: g0: w_hh[c][kk], g1: w_hh[150+c][kk], g3: w_hh[300+c][kk], g2: 0
__global__ void build_B_kernel(const float* __restrict__ wih, const float* __restrict__ whh,
                               const float* __restrict__ eW,
                               u16* __restrict__ Bh, u16* __restrict__ Bl) {
  int id = blockIdx.x * 256 + threadIdx.x;
  if (id >= VC * KB) return;
  int v = id / KB, k = id % KB;
  int g = (v >> 4) & 3, c = (v >> 6) * 16 + (v & 15);
  int seg = k / 160, kk = k % 160;
  float val = 0.f;
  if (c < H && kk < H) {
    if (seg < 2) {
      if (g < 3) {
        const float* wr = wih + (size_t)(g * H + c) * H;
        const float* wc = eW + (size_t)seg * H * H + kk;
        float acc = 0.f;
        for (int t = 0; t < H; t++) acc += wr[t] * wc[(size_t)t * H];
        val = acc;
      }
    } else {
      if (g == 0) val = whh[(size_t)c * H + kk];
      else if (g == 1) val = whh[(size_t)(H + c) * H + kk];
      else if (g == 3) val = whh[(size_t)(2 * H + c) * H + kk];
    }
  }
  u16 h = f2bf_rn(val);
  Bh[id] = h;
  Bl[id] = f2bf_rn(val - bf2f(h));
}

// coefs[0][g*160+c] = W_ihg @ b0 (deg0 coef), coefs[1] = W_ihg @ b1, coefs[2] = gate bias
__global__ void build_coef_kernel(const float* __restrict__ wih,
                                  const float* __restrict__ eb,
                                  const float* __restrict__ bih, const float* __restrict__ bhh,
                                  float* __restrict__ coefs) {
  int id = threadIdx.x + blockIdx.x * 256;
  if (id >= VC) return;
  int g = id / 160, c = id % 160;
  float u0 = 0.f, u1 = 0.f, bs = 0.f;
  if (c < H) {
    if (g < 3) {
      const float* wr = wih + (size_t)(g * H + c) * H;
      for (int t = 0; t < H; t++) { u0 += wr[t] * eb[t]; u1 += wr[t] * eb[H + t]; }
    }
    if (g == 0) bs = bih[c] + bhh[c];
    else if (g == 1) bs = bih[H + c] + bhh[H + c];
    else if (g == 2) bs = bih[2 * H + c];
    else bs = bhh[2 * H + c];
  }
  coefs[id] = u0;
  coefs[VC + id] = u1;
  coefs[2 * VC + id] = bs;
}

// pack input nodes into npkA; zero pad cols of both buffers
__global__ void init_nodes_kernel(const float* __restrict__ nin,
                                  u32* __restrict__ npkA, u32* __restrict__ npkB) {
  int id = blockIdx.x * 256 + threadIdx.x;
  if (id >= NN * 160) return;
  int r = id / 160, c = id % 160;
  if (c < H) {
    npkA[id] = packf(nin[(size_t)r * H + c]);
  } else {
    npkA[id] = 0;
    npkB[id] = 0;
  }
}

// zero the pad columns of packed S (cols 150..159 per set) — gather never writes them
__global__ void pad_S_kernel(u32* __restrict__ Snp) {
  int id = blockIdx.x * 256 + threadIdx.x;
  if (id >= NN * 20) return;
  int r = id / 20, rem = id % 20;
  int set = rem / 10, t = rem % 10;
  Snp[(size_t)r * 320 + set * 160 + H + t] = 0;
}

// ---------------- gather: Snp[n][set*160+c] = packed sum of raw node rows ------
// R14 structure kept: adjacency list loaded coalesced once, src broadcast via
// readlane, 4-edge unroll. Bit-identical accumulation order.
__global__ __launch_bounds__(256) void gather_kernel(
    const u32* __restrict__ npk, const int* __restrict__ rowptr,
    const u16* __restrict__ colbuf, u32* __restrict__ Snp) {
  int gtid = blockIdx.x * 256 + threadIdx.x;
  int wid = gtid >> 6;
  if (wid >= 2 * NN) return;
  int node = wid >> 1, set = wid & 1;
  int lane = gtid & 63;
  int s = rowptr[2 * node + set], e = rowptr[2 * node + set + 1];
  int deg = e - s;
  int cA = 2 * lane, cC = 128 + lane;
  bool okC = (cC < H);                 // lanes 0..21
  float aA = 0.f, aB = 0.f, aC = 0.f;
  for (int base = 0; base < deg; base += 64) {
    int rem = min(64, deg - base);
    u32 srcv = 0;
    if (lane < rem) srcv = (u32)colbuf[s + base + lane];
    int i = 0;
    for (; i + 3 < rem; i += 4) {
      u32 r0 = (u32)__builtin_amdgcn_readlane((int)srcv, i);
      u32 r1 = (u32)__builtin_amdgcn_readlane((int)srcv, i + 1);
      u32 r2 = (u32)__builtin_amdgcn_readlane((int)srcv, i + 2);
      u32 r3 = (u32)__builtin_amdgcn_readlane((int)srcv, i + 3);
      const u32* p0 = npk + (size_t)r0 * 160;
      const u32* p1 = npk + (size_t)r1 * 160;
      const u32* p2 = npk + (size_t)r2 * 160;
      const u32* p3 = npk + (size_t)r3 * 160;
      uint2v v0 = *(const uint2v*)(p0 + cA);
      uint2v v1 = *(const uint2v*)(p1 + cA);
      uint2v v2 = *(const uint2v*)(p2 + cA);
      uint2v v3 = *(const uint2v*)(p3 + cA);
      u32 w0 = 0, w1 = 0, w2 = 0, w3 = 0;
      if (okC) { w0 = p0[cC]; w1 = p1[cC]; w2 = p2[cC]; w3 = p3[cC]; }
      aA += upk(v0.x) + upk(v1.x);
      aB += upk(v0.y) + upk(v1.y);
      if (okC) aC += upk(w0) + upk(w1);
      aA += upk(v2.x) + upk(v3.x);
      aB += upk(v2.y) + upk(v3.y);
      if (okC) aC += upk(w2) + upk(w3);
    }
    for (; i + 1 < rem; i += 2) {
      u32 r0 = (u32)__builtin_amdgcn_readlane((int)srcv, i);
      u32 r1 = (u32)__builtin_amdgcn_readlane((int)srcv, i + 1);
      const u32* p0 = npk + (size_t)r0 * 160;
      const u32* p1 = npk + (size_t)r1 * 160;
      uint2v v0 = *(const uint2v*)(p0 + cA);
      uint2v v1 = *(const uint2v*)(p1 + cA);
      aA += upk(v0.x) + upk(v1.x);
      aB += upk(v0.y) + upk(v1.y);
      if (okC) aC += upk(p0[cC]) + upk(p1[cC]);
    }
    if (i < rem) {
      u32 r0 = (u32)__builtin_amdgcn_readlane((int)srcv, i);
      const u32* p0 = npk + (size_t)r0 * 160;
      uint2v v0 = *(const uint2v*)(p0 + cA);
      aA += upk(v0.x);
      aB += upk(v0.y);
      if (okC) aC += upk(p0[cC]);
    }
  }
  u32* o = Snp + (size_t)node * 320 + set * 160;
  o[cA] = packf(aA);
  o[cA + 1] = packf(aB);
  if (okC) o[cC] = packf(aC);
}

// ---------------- fused GRU GEMM — R16: single-buffer LDS, 4 blocks/CU --------
// R15 post-mortem: direct per-lane global loads are uncoalesced (64 lines/instr)
// -> LDS staging is mandatory for coalescing. R11-R13 post-mortem: with 64KB LDS
// only 2 blocks/CU exist; every barrier/waitcnt stalls the whole CU (nothing
// saturated: MFMA ~8%, LDS ~20%, VMEM ~10% of wall). R16 trades in-block
// pipelining for OCCUPANCY: single 32KB buffer set -> 4 blocks/CU (16 waves),
// T3-minimum 2-phase per kt:
//   ds_read frags(kt) -> lgkm(0)+barrier   (write-after-read safe)
//   stage(kt+1) into SAME buffers          (issue early)
//   MFMA(kt) from regs                     (overlaps stage L2 latency)
//   vmcnt(0)+barrier                       (read-after-write safe)
// Cross-block wave overlap (m114) fills each block's drain stall. MFMA order
// and operand values unchanged -> bit-identical output.

template<int KT>
__device__ __forceinline__ void stage_fn(
    const u32* __restrict__ Snp, const u32* __restrict__ npkc,
    const u16* __restrict__ Bhp, const u16* __restrict__ Blp,
    char* Ab, char* Bb, int tid, int w, int r0, int ccb) {
  // A tile: 128 rows x 32 k-cols packed u32 = 128B/row, XOR-swizzled chunks
  #pragma unroll
  for (int i = 0; i < 4; i++) {
    int cl = i * 256 + tid;                     // [0,1024)
    int row = cl >> 3;
    int q = (cl & 7) ^ (row & 7);
    int rg = min(r0 + row, NN - 1);
    if constexpr (KT < 10)
      async16(Snp + (size_t)rg * 320 + KT * 32 + q * 4, Ab + i * 4096 + w * 1024);
    else
      async16(npkc + (size_t)rg * 160 + (KT - 10) * 32 + q * 4, Ab + i * 4096 + w * 1024);
  }
  constexpr int koffB = (KT < 10) ? KT * 32 : 320 + (KT - 10) * 32;
  constexpr int skipg = (KT < 10) ? 3 : 2;      // zero-gate rows (exact skip)
  #pragma unroll
  for (int i = 0; i < 2; i++) {
    int cl = i * 256 + tid;                     // [0,512)
    int row = cl >> 2;
    int q = (cl & 3) ^ ((row >> 1) & 3);
    if (((row >> 4) & 3) != skipg) {            // wave-uniform predicate
      size_t gb = (size_t)(ccb * 128 + row) * KB + koffB + q * 8;
      int lb = i * 4096 + w * 1024;
      async16(Bhp + gb, Bb + lb);
      async16(Blp + gb, Bb + 8192 + lb);
    }
  }
}

template<int KTn>
__device__ __forceinline__ void read_frags_fn(
    const char* Ab, const char* Bb, int m, int quad, int mrow0, int nco0,
    uint4v (&A0)[4], uint4v (&A1)[4], short8 (&RBh)[3], short8 (&RBl)[3]) {
  #pragma unroll
  for (int jj = 0; jj < 3; jj++) {
    const int jsel = (jj == 2) ? ((KTn < 10) ? 2 : 3) : jj;
    int br = nco0 + jsel * 16 + m;
    int bd = br * 64 + ((quad ^ ((br >> 1) & 3)) * 16);
    RBh[jj] = *(const short8*)(Bb + bd);
    RBl[jj] = *(const short8*)(Bb + 8192 + bd);
  }
  #pragma unroll
  for (int mt = 0; mt < 4; mt++) {
    int r = mrow0 + mt * 16 + m;
    A0[mt] = *(const uint4v*)(Ab + r * 128 + (((2 * quad) ^ (r & 7)) * 16));
    A1[mt] = *(const uint4v*)(Ab + r * 128 + (((2 * quad + 1) ^ (r & 7)) * 16));
  }
}

template<int KT>
__device__ __forceinline__ void mfma_fn(
    const uint4v (&A0)[4], const uint4v (&A1)[4],
    const short8 (&MBh)[3], const short8 (&MBl)[3], float4v (&acc)[4][4]) {
  #pragma unroll
  for (int mt = 0; mt < 4; mt++) {
    u32 uu[8] = {A0[mt].x, A0[mt].y, A0[mt].z, A0[mt].w,
                 A1[mt].x, A1[mt].y, A1[mt].z, A1[mt].w};
    short8 ah, al;
    #pragma unroll
    for (int e2 = 0; e2 < 8; e2++) {
      ah[e2] = (short)(uu[e2] & 0xffffu);
      al[e2] = (short)(uu[e2] >> 16);
    }
    #pragma unroll
    for (int jj = 0; jj < 3; jj++) {
      const int J = (KT < 10) ? jj : ((jj == 2) ? 3 : jj);
      acc[mt][J] = __builtin_amdgcn_mfma_f32_16x16x32_bf16(ah, MBh[jj], acc[mt][J], 0, 0, 0);
      acc[mt][J] = __builtin_amdgcn_mfma_f32_16x16x32_bf16(ah, MBl[jj], acc[mt][J], 0, 0, 0);
      acc[mt][J] = __builtin_amdgcn_mfma_f32_16x16x32_bf16(al, MBh[jj], acc[mt][J], 0, 0, 0);
    }
  }
}

template<int KT>
__device__ __forceinline__ void gemm_step(
    const u32* __restrict__ Snp, const u32* __restrict__ npkc,
    const u16* __restrict__ Bhp, const u16* __restrict__ Blp,
    char (&Abuf)[16384], char (&Bbuf)[16384],
    int tid, int w, int m, int quad, int mrow0, int nco0, int r0, int ccb,
    float4v (&acc)[4][4]) {
  uint4v A0[4], A1[4];
  short8 FBh[3], FBl[3];
  // 1. read frags(KT) from the single buffer
  read_frags_fn<KT>(Abuf, Bbuf, m, quad, mrow0, nco0, A0, A1, FBh, FBl);
  asm volatile("s_waitcnt lgkmcnt(0)" ::: "memory");
  __builtin_amdgcn_sched_barrier(0);
  __builtin_amdgcn_s_barrier();                 // all waves done reading buffer
  // 2. stage(KT+1) into the same buffer (issue early, latency hidden by MFMA)
  if constexpr (KT + 1 <= 14)
    stage_fn<KT + 1>(Snp, npkc, Bhp, Blp, Abuf, Bbuf, tid, w, r0, ccb);
  __builtin_amdgcn_sched_barrier(0);
  // 3. MFMA(KT) from regs (matrix pipe runs while stage loads are in flight)
  __builtin_amdgcn_s_setprio(1);
  mfma_fn<KT>(A0, A1, FBh, FBl, acc);
  __builtin_amdgcn_s_setprio(0);
  __builtin_amdgcn_sched_barrier(0);
  // 4. stage(KT+1) complete before next step's reads
  if constexpr (KT + 1 <= 14) {
    asm volatile("s_waitcnt vmcnt(0)" ::: "memory");
    __builtin_amdgcn_sched_barrier(0);
    __builtin_amdgcn_s_barrier();
  }
}

__global__ __launch_bounds__(256, 4) void gru_gemm_kernel(
    const u32* __restrict__ Snp, const u32* __restrict__ npkc,
    const u16* __restrict__ Bhp, const u16* __restrict__ Blp,
    const float* __restrict__ coefs, const int* __restrict__ rowptr,
    u32* __restrict__ npkn) {
  __shared__ char Abuf[16384];  // packed u32 A tile: 128 rows x 128B, XOR swizzle
  __shared__ char Bbuf[16384];  // [0,8K)=hi, [8K,16K)=lo
  const int bid = blockIdx.x;
  const int xcd = bid & 7;
  const int rest = bid >> 3;
  const int ccb = rest % 5;
  const int r0b = (rest / 5) * 8 + xcd;
  if (r0b >= NRB) return;
  const int r0 = r0b * 128;
  const int tid = threadIdx.x;
  const int w = tid >> 6, l = tid & 63;
  const int m = l & 15, quad = l >> 4;
  const int mrow0 = (w & 1) * 64;
  const int nco0 = (w >> 1) * 64;

  float4v acc[4][4];
  #pragma unroll
  for (int mt = 0; mt < 4; mt++)
    #pragma unroll
    for (int j = 0; j < 4; j++) acc[mt][j] = (float4v){0.f, 0.f, 0.f, 0.f};

  // ---- prologue: stage kt=0, drain, barrier ----
  stage_fn<0>(Snp, npkc, Bhp, Blp, Abuf, Bbuf, tid, w, r0, ccb);
  asm volatile("s_waitcnt vmcnt(0)" ::: "memory");
  __builtin_amdgcn_sched_barrier(0);
  __builtin_amdgcn_s_barrier();

  // ---- 15 fully-unrolled K-steps, 2 barriers each ----
  #define STEP(K) gemm_step<K>(Snp, npkc, Bhp, Blp, Abuf, Bbuf, tid, w, m, quad, \
                               mrow0, nco0, r0, ccb, acc)
  STEP(0);  STEP(1);  STEP(2);  STEP(3);  STEP(4);
  STEP(5);  STEP(6);  STEP(7);  STEP(8);  STEP(9);
  STEP(10); STEP(11); STEP(12); STEP(13); STEP(14);
  #undef STEP

  // ---- epilogue: wave handles c-chunk cc = ccb*2 + (w>>1); tile j = gate ----
  int c = (ccb * 2 + (w >> 1)) * 16 + m;
  if (c >= H) return;
  float u0r = coefs[c],            u0z = coefs[160 + c],
        u0n = coefs[320 + c];
  float u1r = coefs[VC + c],       u1z = coefs[VC + 160 + c],
        u1n = coefs[VC + 320 + c];
  float bsr = coefs[2 * VC + c],   bsz = coefs[2 * VC + 160 + c],
        bsn = coefs[2 * VC + 320 + c], bsh = coefs[2 * VC + 480 + c];
  #pragma unroll
  for (int mt = 0; mt < 4; mt++) {
    #pragma unroll
    for (int i = 0; i < 4; i++) {
      int row = r0 + mrow0 + mt * 16 + quad * 4 + i;
      if (row >= NN) continue;
      float d0 = (float)(rowptr[2 * row + 1] - rowptr[2 * row]);
      float d1 = (float)(rowptr[2 * row + 2] - rowptr[2 * row + 1]);
      float pr = acc[mt][0][i] + d0 * u0r + d1 * u1r + bsr;
      float pz = acc[mt][1][i] + d0 * u0z + d1 * u1z + bsz;
      float pn = acc[mt][2][i] + d0 * u0n + d1 * u1n + bsn;
      float ph = acc[mt][3][i] + bsh;
      float r_g = 1.f / (1.f + __expf(-pr));
      float z_g = 1.f / (1.f + __expf(-pz));
      float narg = pn + r_g * ph;
      float e2 = __expf(2.f * narg);
      float n_g = 1.f - 2.f / (e2 + 1.f);       // tanh, inf-safe
      float h = upk(npkc[(size_t)row * 160 + c]);
      npkn[(size_t)row * 160 + c] = packf((1.f - z_g) * n_g + z_g * h);
    }
  }
}

// ---------------- readout ----------------
__global__ __launch_bounds__(192) void segsum_kernel(const u32* __restrict__ npk,
                                                     const int* __restrict__ gstart,
                                                     float* __restrict__ gsum) {
  int g = blockIdx.x, chunk = blockIdx.y;
  int c = threadIdx.x;
  if (c >= H) return;
  int s = gstart[g], e = gstart[g + 1];
  int len = e - s;
  if (len <= 0) return;
  int per = (len + 3) / 4;
  int rs = s + chunk * per;
  int re = min(e, rs + per);
  if (rs >= re) return;
  float acc = 0.f;
  for (int r = rs; r < re; r++) acc += upk(npk[(size_t)r * 160 + c]);
  atomicAdd(&gsum[g * H + c], acc);
}

// one block per graph row; 192 thr. LDS: x[151], x1[80], x2[80].
__global__ __launch_bounds__(192) void head_kernel(
    const float* __restrict__ gsum, const float* __restrict__ pt,
    const float* __restrict__ fc1_w, const float* __restrict__ fc1_b,
    const float* __restrict__ fc2_w, const float* __restrict__ fc2_b,
    const float* __restrict__ fcL_w, const float* __restrict__ fcL_b,
    float* __restrict__ out) {
  __shared__ float x[151];
  __shared__ float x1[80];
  __shared__ float x2[80];
  int row = blockIdx.x;
  int t = threadIdx.x;
  if (t < 151) {
    float v;
    if (t < H) { float g = gsum[row * H + t]; v = (g > 1.f) ? logf(g) : 0.f; }
    else v = pt[row];
    x[t] = v;
  }
  __syncthreads();
  if (t < 80) {
    float acc = fc1_b[t];
    const float* wrow = fc1_w + t * 151;
    #pragma unroll 4
    for (int k = 0; k < 151; k++) acc += x[k] * wrow[k];
    x1[t] = (acc > 0.f) ? acc : 0.01f * acc;
  }
  __syncthreads();
  if (t < 80) {
    float acc = fc2_b[t];
    const float* wrow = fc2_w + t * 80;
    #pragma unroll 4
    for (int k = 0; k < 80; k++) acc += x1[k] * wrow[k];
    x2[t] = (acc > 0.f) ? acc : 0.01f * acc;
  }
  __syncthreads();
  if (t < 10) {
    float acc = fcL_b[t];
    const float* wrow = fcL_w + t * 80;
    #pragma unroll 4
    for (int k = 0; k < 80; k++) acc += x2[k] * wrow[k];
    out[row * 10 + t] = acc;
  }
}

extern "C" void kernel_launch(void* const* d_in, const int* in_sizes, int n_in,
                              void* d_out, int out_size, void* d_ws, size_t ws_size,
                              hipStream_t stream) {
  const float* nodes_in = (const float*)d_in[0];
  const float* problem_type = (const float*)d_in[1];
  const float* edge_W = (const float*)d_in[2];
  const float* edge_b = (const float*)d_in[3];
  const float* w_ih = (const float*)d_in[4];
  const float* w_hh = (const float*)d_in[5];
  const float* b_ih = (const float*)d_in[6];
  const float* b_hh = (const float*)d_in[7];
  const float* fc1_w = (const float*)d_in[8];
  const float* fc1_b = (const float*)d_in[9];
  const float* fc2_w = (const float*)d_in[10];
  const float* fc2_b = (const float*)d_in[11];
  const float* fcL_w = (const float*)d_in[12];
  const float* fcL_b = (const float*)d_in[13];
  const int* edges = (const int*)d_in[14];
  const int* graph_ids = (const int*)d_in[15];

  char* ws = (char*)d_ws;
  size_t off = 0;
  auto alloc = [&](size_t bytes) -> void* {
    void* p = ws + off;
    off = (off + bytes + 255) & ~(size_t)255;
    return p;
  };
  u32* npkA     = (u32*)alloc((size_t)NN * 160 * 4);           // 32 MB
  u32* npkB     = (u32*)alloc((size_t)NN * 160 * 4);           // 32 MB
  u32* Snp      = (u32*)alloc((size_t)NN * 320 * 4);           // 64 MB packed S
  u16* Bh       = (u16*)alloc((size_t)VC * KB * 2);            // 0.61 MB
  u16* Bl       = (u16*)alloc((size_t)VC * KB * 2);            // 0.61 MB
  float* coefs  = (float*)alloc(3 * VC * 4);
  int* rowptr   = (int*)alloc((2 * NN + 1) * 4);
  int* cursor   = (int*)alloc(2 * NN * 4);
  u16* colbuf   = (u16*)alloc(2ull * NE * 2);                  // 1.6 MB
  int* bsum     = (int*)alloc(128 * 4);
  int* boff     = (int*)alloc(128 * 4);
  int* gstart   = (int*)alloc((NG + 1) * 4);
  float* gsum   = (float*)alloc((size_t)NG * H * 4);

  const int n2 = 2 * NN;                 // 100000 counters
  const int nb = (n2 + 1023) / 1024;     // 98 scan blocks

  // ---- one-time setup ----
  hipMemsetAsync(cursor, 0, n2 * 4, stream);
  hist_kernel<<<(2 * NE + 255) / 256, 256, 0, stream>>>(edges, cursor);
  scan1_kernel<<<nb, 1024, 0, stream>>>(cursor, rowptr, bsum, n2);
  scan2_kernel<<<1, 128, 0, stream>>>(bsum, boff, nb);
  scan3_kernel<<<(n2 + 255) / 256, 256, 0, stream>>>(rowptr, boff, n2);
  total_kernel<<<1, 64, 0, stream>>>(rowptr, boff, n2, nb);
  copy_int_kernel<<<(n2 + 255) / 256, 256, 0, stream>>>(rowptr, cursor, n2);
  fill_kernel<<<(2 * NE + 255) / 256, 256, 0, stream>>>(edges, cursor, colbuf);
  bounds_kernel<<<1, 128, 0, stream>>>(graph_ids, gstart);
  build_B_kernel<<<(VC * KB + 255) / 256, 256, 0, stream>>>(w_ih, w_hh, edge_W, Bh, Bl);
  build_coef_kernel<<<(VC + 255) / 256, 256, 0, stream>>>(w_ih, edge_b, b_ih, b_hh, coefs);
  init_nodes_kernel<<<(NN * 160 + 255) / 256, 256, 0, stream>>>(nodes_in, npkA, npkB);
  pad_S_kernel<<<(NN * 20 + 255) / 256, 256, 0, stream>>>(Snp);

  // ---- 5 message-passing iterations (packed nodes ping-pong) ----
  const int ngrp = (NRB + 7) / 8;        // 49 groups of 8 row-blocks
  u32* nbuf[2] = {npkA, npkB};
  for (int pass = 0; pass < NPASS; pass++) {
    u32* cur = nbuf[pass & 1];
    u32* nxt = nbuf[1 - (pass & 1)];
    gather_kernel<<<(2 * NN * 64 + 255) / 256, 256, 0, stream>>>(cur, rowptr, colbuf, Snp);
    gru_gemm_kernel<<<ngrp * 5 * 8, 256, 0, stream>>>(
        Snp, cur, Bh, Bl, coefs, rowptr, nxt);
  }
  u32* fin = nbuf[NPASS & 1];

  // ---- readout ----
  hipMemsetAsync(gsum, 0, (size_t)NG * H * 4, stream);
  segsum_kernel<<<dim3(NG, 4), 192, 0, stream>>>(fin, gstart, gsum);
  head_kernel<<<NG, 192, 0, stream>>>(gsum, problem_type, fc1_w, fc1_b, fc2_w, fc2_b,
                                      fcL_w, fcL_b, (float*)d_out);
}